// Round 13
// baseline (146.540 us; speedup 1.0000x reference)
//
#include <hip/hip_runtime.h>
#include <hip/hip_bf16.h>
#include <cstddef>
#include <cstdint>

// LinearAttention fused pipeline, MI355X gfx950.  == MEASUREMENT ROUND ==
// Identical to R12 except k_q_exp128 is launched 5x (idempotent) to measure
// its true duration: dur = (T13 - T12) / 4. If dur > ~40us it also surfaces
// in rocprof top-5 with its own counters.
// R12 ledger is inconsistent (R3 vs R6 subtraction conflict; R7 mega=47us
// moving only 43MB with nothing saturated) -> need one direct number.

typedef __attribute__((ext_vector_type(8))) short short8_t;
typedef __attribute__((ext_vector_type(4))) float f32x4;

#define SCALE_Q 0.17677669529663687f
#define EPS_LN 1e-5f

__device__ __forceinline__ float bf2f(unsigned short u) {
  union { float f; unsigned u; } v; v.u = ((unsigned)u) << 16;
  return v.f;
}
__device__ __forceinline__ unsigned pack2(float f0, float f1) {
  union { float f; unsigned u; } a, b; a.f = f0; b.f = f1;
  return __builtin_amdgcn_perm(b.u, a.u, 0x07060302);
}
__device__ __forceinline__ unsigned short f2bf_rne(float f) {
  union { float f; unsigned u; } v; v.f = f;
  return (unsigned short)((v.u + 0x7FFFu + ((v.u >> 16) & 1u)) >> 16);
}
__device__ __forceinline__ unsigned pack2rne(float f0, float f1) {
  return (unsigned)f2bf_rne(f0) | ((unsigned)f2bf_rne(f1) << 16);
}
__device__ __forceinline__ short8_t trunc8(float4 lo, float4 hi) {
  union { float4 f; unsigned u[4]; } a, b;
  union { unsigned u[4]; short8_t s; } r;
  a.f = lo; b.f = hi;
  r.u[0] = __builtin_amdgcn_perm(a.u[1], a.u[0], 0x07060302);
  r.u[1] = __builtin_amdgcn_perm(a.u[3], a.u[2], 0x07060302);
  r.u[2] = __builtin_amdgcn_perm(b.u[1], b.u[0], 0x07060302);
  r.u[3] = __builtin_amdgcn_perm(b.u[3], b.u[2], 0x07060302);
  return r.s;
}

// ---------------- K1: transpose + bf16 convert w_qkv [128][384] -> [384][128]
__global__ void k_transpose_wqkv(const float* __restrict__ w,
                                 unsigned short* __restrict__ wT) {
  int c = blockIdx.x * 4 + (threadIdx.x >> 6);
  int l = threadIdx.x & 63;
  float f0 = w[(size_t)(2 * l) * 384 + c];
  float f1 = w[(size_t)(2 * l + 1) * 384 + c];
  ((unsigned*)(wT + (size_t)c * 128))[l] = pack2(f0, f1);
}

// ---------------- K2: q GEMM (kv_ctx clone) -> eq = exp(q) unnormalized
__global__ __launch_bounds__(256, 2)
void k_q_exp128(const float* __restrict__ x, const unsigned short* __restrict__ wT,
                unsigned short* __restrict__ eq) {
  __shared__ short Bq[128][136];

  int tid = threadIdx.x;
  int rowBase = blockIdx.x * 128;

  {
#pragma unroll
    for (int i = 0; i < 8; ++i) {
      int idx = i * 256 + tid;
      int n = idx >> 4;
      int k8 = (idx & 15) << 3;
      *(short8_t*)&Bq[n][k8] = *(const short8_t*)(wT + (size_t)n * 128 + k8);
    }
  }

  int lane = tid & 63;
  int wv = tid >> 6;
  int wr = wv >> 1, wc = wv & 1;
  int lr = lane & 15;
  int kg = lane >> 4;

  short8_t abf[4][4];
  {
    const float* ap = x + (size_t)(rowBase + wr * 64 + lr) * 128 + kg * 8;
#pragma unroll
    for (int mf = 0; mf < 4; ++mf) {
      const float* r = ap + (size_t)mf * 16 * 128;
#pragma unroll
      for (int kk = 0; kk < 4; ++kk)
        abf[kk][mf] = trunc8(*(const float4*)(r + kk * 32),
                             *(const float4*)(r + kk * 32 + 4));
    }
  }
  __syncthreads();

  f32x4 acc[4][4] = {};
#pragma unroll
  for (int kk = 0; kk < 4; ++kk) {
    short8_t bf[4];
#pragma unroll
    for (int nf = 0; nf < 4; ++nf)
      bf[nf] = *(const short8_t*)&Bq[wc * 64 + nf * 16 + lr][kk * 32 + kg * 8];
#pragma unroll
    for (int mf = 0; mf < 4; ++mf)
#pragma unroll
      for (int nf = 0; nf < 4; ++nf)
        acc[mf][nf] = __builtin_amdgcn_mfma_f32_16x16x32_bf16(abf[kk][mf], bf[nf], acc[mf][nf], 0, 0, 0);
  }

#pragma unroll
  for (int mf = 0; mf < 4; ++mf)
#pragma unroll
    for (int p = 0; p < 2; ++p)
#pragma unroll
      for (int j = 0; j < 4; ++j) {
        float e0 = __expf(acc[mf][2 * p][j]);
        float e1 = __expf(acc[mf][2 * p + 1][j]);
        int tok = rowBase + wr * 64 + mf * 16 + kg * 4 + j;
        int head = wc * 2 + p;
        *(unsigned*)&eq[(size_t)tok * 128 + head * 32 + 2 * lr] = pack2(e0, e1);
      }
}

// ---------------- K3: k+v GEMMs + in-tile ctx partial (R3/R5-exact)
__global__ __launch_bounds__(256, 2)
void k_kv_ctx(const float* __restrict__ x, const unsigned short* __restrict__ wT,
              float* __restrict__ ctxp, float* __restrict__ ksump) {
  __shared__ short Bk[128][136];
  __shared__ short Bv[128][136];

  int tid = threadIdx.x;
  int rb = blockIdx.x;
  int rowBase = rb * 128;

  {
    const unsigned short* wk = wT + (size_t)1 * 128 * 128;
    const unsigned short* wv2 = wT + (size_t)2 * 128 * 128;
#pragma unroll
    for (int i = 0; i < 8; ++i) {
      int idx = i * 256 + tid;
      int n = idx >> 4;
      int k8 = (idx & 15) << 3;
      *(short8_t*)&Bk[n][k8] = *(const short8_t*)(wk + (size_t)n * 128 + k8);
      *(short8_t*)&Bv[n][k8] = *(const short8_t*)(wv2 + (size_t)n * 128 + k8);
    }
  }

  int lane = tid & 63;
  int wv = tid >> 6;
  int wr = wv >> 1, wc = wv & 1;
  int lr = lane & 15;
  int kg = lane >> 4;

  short8_t abf[4][4];
  {
    const float* ap = x + (size_t)(rowBase + wr * 64 + lr) * 128 + kg * 8;
#pragma unroll
    for (int mf = 0; mf < 4; ++mf) {
      const float* r = ap + (size_t)mf * 16 * 128;
#pragma unroll
      for (int kk = 0; kk < 4; ++kk)
        abf[kk][mf] = trunc8(*(const float4*)(r + kk * 32),
                             *(const float4*)(r + kk * 32 + 4));
    }
  }
  __syncthreads();

  uint2 ekp[4][4], vp[4][4];
  {
    f32x4 acc[4][4] = {};
#pragma unroll
    for (int kk = 0; kk < 4; ++kk) {
      short8_t bf[4];
#pragma unroll
      for (int nf = 0; nf < 4; ++nf)
        bf[nf] = *(const short8_t*)&Bk[wc * 64 + nf * 16 + lr][kk * 32 + kg * 8];
#pragma unroll
      for (int mf = 0; mf < 4; ++mf)
#pragma unroll
        for (int nf = 0; nf < 4; ++nf)
          acc[mf][nf] = __builtin_amdgcn_mfma_f32_16x16x32_bf16(abf[kk][mf], bf[nf], acc[mf][nf], 0, 0, 0);
    }
#pragma unroll
    for (int mf = 0; mf < 4; ++mf)
#pragma unroll
      for (int nf = 0; nf < 4; ++nf) {
        ekp[mf][nf].x = pack2(__expf(acc[mf][nf][0]), __expf(acc[mf][nf][1]));
        ekp[mf][nf].y = pack2(__expf(acc[mf][nf][2]), __expf(acc[mf][nf][3]));
      }
  }
  {
    f32x4 acc[4][4] = {};
#pragma unroll
    for (int kk = 0; kk < 4; ++kk) {
      short8_t bf[4];
#pragma unroll
      for (int nf = 0; nf < 4; ++nf)
        bf[nf] = *(const short8_t*)&Bv[wc * 64 + nf * 16 + lr][kk * 32 + kg * 8];
#pragma unroll
      for (int mf = 0; mf < 4; ++mf)
#pragma unroll
        for (int nf = 0; nf < 4; ++nf)
          acc[mf][nf] = __builtin_amdgcn_mfma_f32_16x16x32_bf16(abf[kk][mf], bf[nf], acc[mf][nf], 0, 0, 0);
    }
#pragma unroll
    for (int mf = 0; mf < 4; ++mf)
#pragma unroll
      for (int nf = 0; nf < 4; ++nf) {
        vp[mf][nf].x = pack2(acc[mf][nf][0], acc[mf][nf][1]);
        vp[mf][nf].y = pack2(acc[mf][nf][2], acc[mf][nf][3]);
      }
  }
  __syncthreads();

  short (*ekT)[136] = Bk;
  short (*vT)[136] = Bv;
#pragma unroll
  for (int mf = 0; mf < 4; ++mf) {
    int t0 = wr * 64 + mf * 16 + kg * 4;
#pragma unroll
    for (int nf = 0; nf < 4; ++nf) {
      int col = wc * 64 + nf * 16 + lr;
      *(uint2*)&ekT[col][t0] = ekp[mf][nf];
      *(uint2*)&vT[col][t0] = vp[mf][nf];
    }
  }
  __syncthreads();

  {
    int h = wv;
    f32x4 c2[2][2] = {};
#pragma unroll
    for (int kk = 0; kk < 4; ++kk) {
      short8_t a2[2], b2[2];
#pragma unroll
      for (int m2 = 0; m2 < 2; ++m2)
        a2[m2] = *(const short8_t*)&ekT[h * 32 + m2 * 16 + lr][kk * 32 + kg * 8];
#pragma unroll
      for (int n2 = 0; n2 < 2; ++n2)
        b2[n2] = *(const short8_t*)&vT[h * 32 + n2 * 16 + lr][kk * 32 + kg * 8];
#pragma unroll
      for (int m2 = 0; m2 < 2; ++m2)
#pragma unroll
        for (int n2 = 0; n2 < 2; ++n2)
          c2[m2][n2] = __builtin_amdgcn_mfma_f32_16x16x32_bf16(a2[m2], b2[n2], c2[m2][n2], 0, 0, 0);
    }
    float* cp = ctxp + ((size_t)rb * 4 + h) * 1024;
#pragma unroll
    for (int m2 = 0; m2 < 2; ++m2)
#pragma unroll
      for (int n2 = 0; n2 < 2; ++n2)
#pragma unroll
        for (int j = 0; j < 4; ++j)
          cp[(m2 * 16 + kg * 4 + j) * 32 + n2 * 16 + lr] = c2[m2][n2][j];
  }

  if (tid < 128) {
    float s = 0;
#pragma unroll
    for (int t8 = 0; t8 < 128; t8 += 8) {
      short8_t v8 = *(const short8_t*)&ekT[tid][t8];
#pragma unroll
      for (int i = 0; i < 8; ++i) s += bf2f((unsigned short)v8[i]);
    }
    ksump[(size_t)rb * 128 + tid] = s;
  }
}

// ---------------- K4: normalize eq in place, per (token,head) 64B chunk
__global__ void k_eqnorm(unsigned short* __restrict__ eq) {
  int idx = blockIdx.x * 256 + threadIdx.x;
  uint4* p = (uint4*)(eq + (size_t)idx * 32);
  uint4 v[4];
#pragma unroll
  for (int t = 0; t < 4; ++t) v[t] = p[t];

  float f[32];
#pragma unroll
  for (int t = 0; t < 4; ++t) {
    const unsigned* u = (const unsigned*)&v[t];
#pragma unroll
    for (int q = 0; q < 4; ++q) {
      f[t * 8 + 2 * q]     = bf2f((unsigned short)(u[q] & 0xFFFFu));
      f[t * 8 + 2 * q + 1] = bf2f((unsigned short)(u[q] >> 16));
    }
  }
  float s = 0;
#pragma unroll
  for (int i = 0; i < 32; ++i) s += f[i];
  float r = SCALE_Q / s;

#pragma unroll
  for (int t = 0; t < 4; ++t) {
    unsigned* u = (unsigned*)&v[t];
#pragma unroll
    for (int q = 0; q < 4; ++q)
      u[q] = pack2rne(f[t * 8 + 2 * q] * r, f[t * 8 + 2 * q + 1] * r);
  }
#pragma unroll
  for (int t = 0; t < 4; ++t) p[t] = v[t];
}

// ---------------- K5: per (b,h) reduce partials + build W_eff^T cols
__global__ __launch_bounds__(256, 4)
void k_weff64(const float* __restrict__ ctxp, const float* __restrict__ ksump,
              const float* __restrict__ wout, unsigned short* __restrict__ weffT) {
  __shared__ float wo[32][128];
  __shared__ float cn[32][32];
  __shared__ float ksh[32];
  int tid = threadIdx.x;
  int b = blockIdx.x >> 2, h = blockIdx.x & 3;

#pragma unroll
  for (int i = 0; i < 16; ++i) {
    int idx = i * 256 + tid;
    int e = idx >> 7, jj = idx & 127;
    wo[e][jj] = wout[(h * 32 + e) * 128 + jj];
  }
  if (tid < 32) {
    float s = 0;
    for (int c = 0; c < 32; ++c)
      s += ksump[(size_t)(b * 32 + c) * 128 + h * 32 + tid];
    ksh[tid] = s;
  }
  __syncthreads();
#pragma unroll
  for (int i = 0; i < 4; ++i) {
    int idx = i * 256 + tid;
    int d = idx >> 5;
    float s = 0;
    for (int c = 0; c < 32; ++c)
      s += ctxp[((size_t)(b * 32 + c) * 4 + h) * 1024 + idx];
    cn[d][idx & 31] = s / ksh[d];
  }
  __syncthreads();

  int j = tid >> 1, h8 = (tid & 1) * 8;
  unsigned pk[8];
#pragma unroll
  for (int t = 0; t < 8; ++t) {
    int dd = h8 + t;
    float s0 = 0, s1 = 0;
#pragma unroll
    for (int e = 0; e < 32; ++e) {
      float w = wo[e][j];
      s0 += cn[dd][e] * w;
      s1 += cn[16 + dd][e] * w;
    }
    pk[t] = pack2(s0, s1);
  }
  unsigned* outp = (unsigned*)(weffT + (size_t)b * 16384 + j * 128 + h * 32 + 2 * h8);
  *(uint4*)outp = make_uint4(pk[0], pk[1], pk[2], pk[3]);
  *(uint4*)(outp + 4) = make_uint4(pk[4], pk[5], pk[6], pk[7]);
}

// ---------------- K6: out = LN( eq @ W_eff[b] + b_out )
__global__ __launch_bounds__(256, 2)
void k_out_ln(const unsigned short* __restrict__ eq, const unsigned short* __restrict__ weffT,
              const float* __restrict__ b_out, const float* __restrict__ g_ln,
              const float* __restrict__ b_ln, float* __restrict__ out) {
  int tid = threadIdx.x;
  int rowBase = blockIdx.x * 128;
  int b = rowBase >> 12;
  int lane = tid & 63;
  int w = tid >> 6;
  int lr = lane & 15;
  int kg = lane >> 4;

  const unsigned short* bb = weffT + (size_t)b * 16384;

  short8_t a[2][4];
  {
    const unsigned short* ap = eq + (size_t)(rowBase + w * 32 + lr) * 128 + kg * 8;
#pragma unroll
    for (int mf = 0; mf < 2; ++mf)
#pragma unroll
      for (int kk = 0; kk < 4; ++kk)
        a[mf][kk] = *(const short8_t*)(ap + (size_t)mf * 16 * 128 + kk * 32);
  }

  f32x4 acc[2][8] = {};
#pragma unroll
  for (int kk = 0; kk < 4; ++kk) {
    short8_t bf[8];
#pragma unroll
    for (int nf = 0; nf < 8; ++nf)
      bf[nf] = *(const short8_t*)(bb + (size_t)(nf * 16 + lr) * 128 + kk * 32 + kg * 8);
#pragma unroll
    for (int mf = 0; mf < 2; ++mf)
#pragma unroll
      for (int nf = 0; nf < 8; ++nf)
        acc[mf][nf] = __builtin_amdgcn_mfma_f32_16x16x32_bf16(a[mf][kk], bf[nf], acc[mf][nf], 0, 0, 0);
  }

  float bo[8], gl[8], bl[8];
#pragma unroll
  for (int nf = 0; nf < 8; ++nf) {
    int c = nf * 16 + lr;
    bo[nf] = b_out[c]; gl[nf] = g_ln[c]; bl[nf] = b_ln[c];
  }
#pragma unroll
  for (int mf = 0; mf < 2; ++mf)
#pragma unroll
    for (int nf = 0; nf < 8; ++nf)
#pragma unroll
      for (int j = 0; j < 4; ++j) acc[mf][nf][j] += bo[nf];

#pragma unroll
  for (int mf = 0; mf < 2; ++mf) {
    float s[4] = {0, 0, 0, 0}, q[4] = {0, 0, 0, 0};
#pragma unroll
    for (int nf = 0; nf < 8; ++nf)
#pragma unroll
      for (int j = 0; j < 4; ++j) {
        float v = acc[mf][nf][j];
        s[j] += v; q[j] += v * v;
      }
#pragma unroll
    for (int j = 0; j < 4; ++j) {
#pragma unroll
      for (int d = 1; d < 16; d <<= 1) {
        s[j] += __shfl_xor(s[j], d, 64);
        q[j] += __shfl_xor(q[j], d, 64);
      }
    }
#pragma unroll
    for (int j = 0; j < 4; ++j) {
      float mean = s[j] * (1.0f / 128.0f);
      float var = q[j] * (1.0f / 128.0f) - mean * mean;
      float rstd = rsqrtf(var + EPS_LN);
      size_t ro = (size_t)(rowBase + w * 32 + mf * 16 + kg * 4 + j) * 128;
#pragma unroll
      for (int nf = 0; nf < 8; ++nf)
        out[ro + nf * 16 + lr] = (acc[mf][nf][j] - mean) * rstd * gl[nf] + bl[nf];
    }
  }
}

extern "C" void kernel_launch(void* const* d_in, const int* in_sizes, int n_in,
                              void* d_out, int out_size, void* d_ws, size_t ws_size,
                              hipStream_t stream) {
  const float* x     = (const float*)d_in[0];
  const float* w_qkv = (const float*)d_in[1];
  const float* w_out = (const float*)d_in[2];
  const float* b_out = (const float*)d_in[3];
  const float* g_ln  = (const float*)d_in[4];
  const float* b_ln  = (const float*)d_in[5];
  float* out = (float*)d_out;

  char* ws = (char*)d_ws;
  unsigned short* wqkvT = (unsigned short*)(ws + 0);
  float* ctxp           = (float*)(ws + 131072);
  float* ksump          = (float*)(ws + 8519680);
  unsigned short* weffT = (unsigned short*)(ws + 8781824);
  unsigned short* eq    = (unsigned short*)(ws + 9306112);

  k_transpose_wqkv<<<96, 256, 0, stream>>>(w_qkv, wqkvT);
  // MEASUREMENT: 5x identical launches (idempotent). dur = (T13 - T12)/4.
  k_q_exp128<<<512, 256, 0, stream>>>(x, wqkvT, eq);
  k_q_exp128<<<512, 256, 0, stream>>>(x, wqkvT, eq);
  k_q_exp128<<<512, 256, 0, stream>>>(x, wqkvT, eq);
  k_q_exp128<<<512, 256, 0, stream>>>(x, wqkvT, eq);
  k_q_exp128<<<512, 256, 0, stream>>>(x, wqkvT, eq);
  k_kv_ctx<<<512, 256, 0, stream>>>(x, wqkvT, ctxp, ksump);
  k_eqnorm<<<1024, 256, 0, stream>>>(eq);
  k_weff64<<<64, 256, 0, stream>>>(ctxp, ksump, w_out, weffT);
  k_out_ln<<<512, 256, 0, stream>>>(eq, weffT, b_out, g_ln, b_ln, out);
}

// Round 14
// 141.112 us; speedup vs baseline: 1.0385x; 1.0385x over previous
//
#include <hip/hip_runtime.h>
#include <hip/hip_bf16.h>
#include <cstddef>
#include <cstdint>

// LinearAttention fused pipeline, MI355X gfx950.  == R14: fix + measure ==
// Change vs R12: (1) k_eqnorm rewritten COALESCED (1 thread = 16 contiguous
// bytes; chunk = 4 adjacent lanes; 2x shfl_xor) — old version was 16B-per-
// lane stride-64 (64 lines/instr, partial-line RMW), suspected ~50us.
// (2) k_kv_ctx launched 5x (idempotent) -> direct dur = contribution/5.
// R13 direct measurement: k_q_exp128 = 14.5us (q-GEMM never was the cost).
// Unified theory: GEMM kernels are fine; sub-line/strided stores are the
// hidden ~25-50us costs (R5 2B-stores, R10 2x WRITE_SIZE, R12 eqnorm).

typedef __attribute__((ext_vector_type(8))) short short8_t;
typedef __attribute__((ext_vector_type(4))) float f32x4;

#define SCALE_Q 0.17677669529663687f
#define EPS_LN 1e-5f

__device__ __forceinline__ float bf2f(unsigned short u) {
  union { float f; unsigned u; } v; v.u = ((unsigned)u) << 16;
  return v.f;
}
__device__ __forceinline__ unsigned pack2(float f0, float f1) {
  union { float f; unsigned u; } a, b; a.f = f0; b.f = f1;
  return __builtin_amdgcn_perm(b.u, a.u, 0x07060302);
}
__device__ __forceinline__ unsigned short f2bf_rne(float f) {
  union { float f; unsigned u; } v; v.f = f;
  return (unsigned short)((v.u + 0x7FFFu + ((v.u >> 16) & 1u)) >> 16);
}
__device__ __forceinline__ unsigned pack2rne(float f0, float f1) {
  return (unsigned)f2bf_rne(f0) | ((unsigned)f2bf_rne(f1) << 16);
}
__device__ __forceinline__ short8_t trunc8(float4 lo, float4 hi) {
  union { float4 f; unsigned u[4]; } a, b;
  union { unsigned u[4]; short8_t s; } r;
  a.f = lo; b.f = hi;
  r.u[0] = __builtin_amdgcn_perm(a.u[1], a.u[0], 0x07060302);
  r.u[1] = __builtin_amdgcn_perm(a.u[3], a.u[2], 0x07060302);
  r.u[2] = __builtin_amdgcn_perm(b.u[1], b.u[0], 0x07060302);
  r.u[3] = __builtin_amdgcn_perm(b.u[3], b.u[2], 0x07060302);
  return r.s;
}

// ---------------- K1: transpose + bf16 convert w_qkv [128][384] -> [384][128]
__global__ void k_transpose_wqkv(const float* __restrict__ w,
                                 unsigned short* __restrict__ wT) {
  int c = blockIdx.x * 4 + (threadIdx.x >> 6);
  int l = threadIdx.x & 63;
  float f0 = w[(size_t)(2 * l) * 384 + c];
  float f1 = w[(size_t)(2 * l + 1) * 384 + c];
  ((unsigned*)(wT + (size_t)c * 128))[l] = pack2(f0, f1);
}

// ---------------- K2: q GEMM (kv_ctx clone) -> eq = exp(q) unnormalized
// MEASURED R13: 14.5us.
__global__ __launch_bounds__(256, 2)
void k_q_exp128(const float* __restrict__ x, const unsigned short* __restrict__ wT,
                unsigned short* __restrict__ eq) {
  __shared__ short Bq[128][136];

  int tid = threadIdx.x;
  int rowBase = blockIdx.x * 128;

  {
#pragma unroll
    for (int i = 0; i < 8; ++i) {
      int idx = i * 256 + tid;
      int n = idx >> 4;
      int k8 = (idx & 15) << 3;
      *(short8_t*)&Bq[n][k8] = *(const short8_t*)(wT + (size_t)n * 128 + k8);
    }
  }

  int lane = tid & 63;
  int wv = tid >> 6;
  int wr = wv >> 1, wc = wv & 1;
  int lr = lane & 15;
  int kg = lane >> 4;

  short8_t abf[4][4];
  {
    const float* ap = x + (size_t)(rowBase + wr * 64 + lr) * 128 + kg * 8;
#pragma unroll
    for (int mf = 0; mf < 4; ++mf) {
      const float* r = ap + (size_t)mf * 16 * 128;
#pragma unroll
      for (int kk = 0; kk < 4; ++kk)
        abf[kk][mf] = trunc8(*(const float4*)(r + kk * 32),
                             *(const float4*)(r + kk * 32 + 4));
    }
  }
  __syncthreads();

  f32x4 acc[4][4] = {};
#pragma unroll
  for (int kk = 0; kk < 4; ++kk) {
    short8_t bf[4];
#pragma unroll
    for (int nf = 0; nf < 4; ++nf)
      bf[nf] = *(const short8_t*)&Bq[wc * 64 + nf * 16 + lr][kk * 32 + kg * 8];
#pragma unroll
    for (int mf = 0; mf < 4; ++mf)
#pragma unroll
      for (int nf = 0; nf < 4; ++nf)
        acc[mf][nf] = __builtin_amdgcn_mfma_f32_16x16x32_bf16(abf[kk][mf], bf[nf], acc[mf][nf], 0, 0, 0);
  }

#pragma unroll
  for (int mf = 0; mf < 4; ++mf)
#pragma unroll
    for (int p = 0; p < 2; ++p)
#pragma unroll
      for (int j = 0; j < 4; ++j) {
        float e0 = __expf(acc[mf][2 * p][j]);
        float e1 = __expf(acc[mf][2 * p + 1][j]);
        int tok = rowBase + wr * 64 + mf * 16 + kg * 4 + j;
        int head = wc * 2 + p;
        *(unsigned*)&eq[(size_t)tok * 128 + head * 32 + 2 * lr] = pack2(e0, e1);
      }
}

// ---------------- K3: k+v GEMMs + in-tile ctx partial (R3/R5-exact)
// Launched 5x this round (idempotent) for direct measurement.
__global__ __launch_bounds__(256, 2)
void k_kv_ctx(const float* __restrict__ x, const unsigned short* __restrict__ wT,
              float* __restrict__ ctxp, float* __restrict__ ksump) {
  __shared__ short Bk[128][136];
  __shared__ short Bv[128][136];

  int tid = threadIdx.x;
  int rb = blockIdx.x;
  int rowBase = rb * 128;

  {
    const unsigned short* wk = wT + (size_t)1 * 128 * 128;
    const unsigned short* wv2 = wT + (size_t)2 * 128 * 128;
#pragma unroll
    for (int i = 0; i < 8; ++i) {
      int idx = i * 256 + tid;
      int n = idx >> 4;
      int k8 = (idx & 15) << 3;
      *(short8_t*)&Bk[n][k8] = *(const short8_t*)(wk + (size_t)n * 128 + k8);
      *(short8_t*)&Bv[n][k8] = *(const short8_t*)(wv2 + (size_t)n * 128 + k8);
    }
  }

  int lane = tid & 63;
  int wv = tid >> 6;
  int wr = wv >> 1, wc = wv & 1;
  int lr = lane & 15;
  int kg = lane >> 4;

  short8_t abf[4][4];
  {
    const float* ap = x + (size_t)(rowBase + wr * 64 + lr) * 128 + kg * 8;
#pragma unroll
    for (int mf = 0; mf < 4; ++mf) {
      const float* r = ap + (size_t)mf * 16 * 128;
#pragma unroll
      for (int kk = 0; kk < 4; ++kk)
        abf[kk][mf] = trunc8(*(const float4*)(r + kk * 32),
                             *(const float4*)(r + kk * 32 + 4));
    }
  }
  __syncthreads();

  uint2 ekp[4][4], vp[4][4];
  {
    f32x4 acc[4][4] = {};
#pragma unroll
    for (int kk = 0; kk < 4; ++kk) {
      short8_t bf[4];
#pragma unroll
      for (int nf = 0; nf < 4; ++nf)
        bf[nf] = *(const short8_t*)&Bk[wc * 64 + nf * 16 + lr][kk * 32 + kg * 8];
#pragma unroll
      for (int mf = 0; mf < 4; ++mf)
#pragma unroll
        for (int nf = 0; nf < 4; ++nf)
          acc[mf][nf] = __builtin_amdgcn_mfma_f32_16x16x32_bf16(abf[kk][mf], bf[nf], acc[mf][nf], 0, 0, 0);
    }
#pragma unroll
    for (int mf = 0; mf < 4; ++mf)
#pragma unroll
      for (int nf = 0; nf < 4; ++nf) {
        ekp[mf][nf].x = pack2(__expf(acc[mf][nf][0]), __expf(acc[mf][nf][1]));
        ekp[mf][nf].y = pack2(__expf(acc[mf][nf][2]), __expf(acc[mf][nf][3]));
      }
  }
  {
    f32x4 acc[4][4] = {};
#pragma unroll
    for (int kk = 0; kk < 4; ++kk) {
      short8_t bf[4];
#pragma unroll
      for (int nf = 0; nf < 4; ++nf)
        bf[nf] = *(const short8_t*)&Bv[wc * 64 + nf * 16 + lr][kk * 32 + kg * 8];
#pragma unroll
      for (int mf = 0; mf < 4; ++mf)
#pragma unroll
        for (int nf = 0; nf < 4; ++nf)
          acc[mf][nf] = __builtin_amdgcn_mfma_f32_16x16x32_bf16(abf[kk][mf], bf[nf], acc[mf][nf], 0, 0, 0);
    }
#pragma unroll
    for (int mf = 0; mf < 4; ++mf)
#pragma unroll
      for (int nf = 0; nf < 4; ++nf) {
        vp[mf][nf].x = pack2(acc[mf][nf][0], acc[mf][nf][1]);
        vp[mf][nf].y = pack2(acc[mf][nf][2], acc[mf][nf][3]);
      }
  }
  __syncthreads();

  short (*ekT)[136] = Bk;
  short (*vT)[136] = Bv;
#pragma unroll
  for (int mf = 0; mf < 4; ++mf) {
    int t0 = wr * 64 + mf * 16 + kg * 4;
#pragma unroll
    for (int nf = 0; nf < 4; ++nf) {
      int col = wc * 64 + nf * 16 + lr;
      *(uint2*)&ekT[col][t0] = ekp[mf][nf];
      *(uint2*)&vT[col][t0] = vp[mf][nf];
    }
  }
  __syncthreads();

  {
    int h = wv;
    f32x4 c2[2][2] = {};
#pragma unroll
    for (int kk = 0; kk < 4; ++kk) {
      short8_t a2[2], b2[2];
#pragma unroll
      for (int m2 = 0; m2 < 2; ++m2)
        a2[m2] = *(const short8_t*)&ekT[h * 32 + m2 * 16 + lr][kk * 32 + kg * 8];
#pragma unroll
      for (int n2 = 0; n2 < 2; ++n2)
        b2[n2] = *(const short8_t*)&vT[h * 32 + n2 * 16 + lr][kk * 32 + kg * 8];
#pragma unroll
      for (int m2 = 0; m2 < 2; ++m2)
#pragma unroll
        for (int n2 = 0; n2 < 2; ++n2)
          c2[m2][n2] = __builtin_amdgcn_mfma_f32_16x16x32_bf16(a2[m2], b2[n2], c2[m2][n2], 0, 0, 0);
    }
    float* cp = ctxp + ((size_t)rb * 4 + h) * 1024;
#pragma unroll
    for (int m2 = 0; m2 < 2; ++m2)
#pragma unroll
      for (int n2 = 0; n2 < 2; ++n2)
#pragma unroll
        for (int j = 0; j < 4; ++j)
          cp[(m2 * 16 + kg * 4 + j) * 32 + n2 * 16 + lr] = c2[m2][n2][j];
  }

  if (tid < 128) {
    float s = 0;
#pragma unroll
    for (int t8 = 0; t8 < 128; t8 += 8) {
      short8_t v8 = *(const short8_t*)&ekT[tid][t8];
#pragma unroll
      for (int i = 0; i < 8; ++i) s += bf2f((unsigned short)v8[i]);
    }
    ksump[(size_t)rb * 128 + tid] = s;
  }
}

// ---------------- K4: COALESCED eq normalization.
// 1 thread = 16 contiguous bytes (8 bf16); chunk (32 bf16) = 4 adjacent
// lanes; sum via shfl_xor(1),shfl_xor(2); rescale; coalesced uint4 store.
// grid 4096 x 256 = 1,048,576 threads = 65536*128/8 elements.
__global__ void k_eqnorm(unsigned short* __restrict__ eq) {
  int idx = blockIdx.x * 256 + threadIdx.x;
  uint4* p = (uint4*)eq + idx;
  uint4 v = *p;
  const unsigned* u = (const unsigned*)&v;
  float f[8];
#pragma unroll
  for (int q = 0; q < 4; ++q) {
    f[2 * q]     = bf2f((unsigned short)(u[q] & 0xFFFFu));
    f[2 * q + 1] = bf2f((unsigned short)(u[q] >> 16));
  }
  float s = 0;
#pragma unroll
  for (int i = 0; i < 8; ++i) s += f[i];
  s += __shfl_xor(s, 1, 64);
  s += __shfl_xor(s, 2, 64);   // 4-lane group total = chunk sum
  float r = SCALE_Q / s;
  unsigned o0 = pack2rne(f[0] * r, f[1] * r);
  unsigned o1 = pack2rne(f[2] * r, f[3] * r);
  unsigned o2 = pack2rne(f[4] * r, f[5] * r);
  unsigned o3 = pack2rne(f[6] * r, f[7] * r);
  *p = make_uint4(o0, o1, o2, o3);
}

// ---------------- K5: per (b,h) reduce partials + build W_eff^T cols
__global__ __launch_bounds__(256, 4)
void k_weff64(const float* __restrict__ ctxp, const float* __restrict__ ksump,
              const float* __restrict__ wout, unsigned short* __restrict__ weffT) {
  __shared__ float wo[32][128];
  __shared__ float cn[32][32];
  __shared__ float ksh[32];
  int tid = threadIdx.x;
  int b = blockIdx.x >> 2, h = blockIdx.x & 3;

#pragma unroll
  for (int i = 0; i < 16; ++i) {
    int idx = i * 256 + tid;
    int e = idx >> 7, jj = idx & 127;
    wo[e][jj] = wout[(h * 32 + e) * 128 + jj];
  }
  if (tid < 32) {
    float s = 0;
    for (int c = 0; c < 32; ++c)
      s += ksump[(size_t)(b * 32 + c) * 128 + h * 32 + tid];
    ksh[tid] = s;
  }
  __syncthreads();
#pragma unroll
  for (int i = 0; i < 4; ++i) {
    int idx = i * 256 + tid;
    int d = idx >> 5;
    float s = 0;
    for (int c = 0; c < 32; ++c)
      s += ctxp[((size_t)(b * 32 + c) * 4 + h) * 1024 + idx];
    cn[d][idx & 31] = s / ksh[d];
  }
  __syncthreads();

  int j = tid >> 1, h8 = (tid & 1) * 8;
  unsigned pk[8];
#pragma unroll
  for (int t = 0; t < 8; ++t) {
    int dd = h8 + t;
    float s0 = 0, s1 = 0;
#pragma unroll
    for (int e = 0; e < 32; ++e) {
      float w = wo[e][j];
      s0 += cn[dd][e] * w;
      s1 += cn[16 + dd][e] * w;
    }
    pk[t] = pack2(s0, s1);
  }
  unsigned* outp = (unsigned*)(weffT + (size_t)b * 16384 + j * 128 + h * 32 + 2 * h8);
  *(uint4*)outp = make_uint4(pk[0], pk[1], pk[2], pk[3]);
  *(uint4*)(outp + 4) = make_uint4(pk[4], pk[5], pk[6], pk[7]);
}

// ---------------- K6: out = LN( eq @ W_eff[b] + b_out )
__global__ __launch_bounds__(256, 2)
void k_out_ln(const unsigned short* __restrict__ eq, const unsigned short* __restrict__ weffT,
              const float* __restrict__ b_out, const float* __restrict__ g_ln,
              const float* __restrict__ b_ln, float* __restrict__ out) {
  int tid = threadIdx.x;
  int rowBase = blockIdx.x * 128;
  int b = rowBase >> 12;
  int lane = tid & 63;
  int w = tid >> 6;
  int lr = lane & 15;
  int kg = lane >> 4;

  const unsigned short* bb = weffT + (size_t)b * 16384;

  short8_t a[2][4];
  {
    const unsigned short* ap = eq + (size_t)(rowBase + w * 32 + lr) * 128 + kg * 8;
#pragma unroll
    for (int mf = 0; mf < 2; ++mf)
#pragma unroll
      for (int kk = 0; kk < 4; ++kk)
        a[mf][kk] = *(const short8_t*)(ap + (size_t)mf * 16 * 128 + kk * 32);
  }

  f32x4 acc[2][8] = {};
#pragma unroll
  for (int kk = 0; kk < 4; ++kk) {
    short8_t bf[8];
#pragma unroll
    for (int nf = 0; nf < 8; ++nf)
      bf[nf] = *(const short8_t*)(bb + (size_t)(nf * 16 + lr) * 128 + kk * 32 + kg * 8);
#pragma unroll
    for (int mf = 0; mf < 2; ++mf)
#pragma unroll
      for (int nf = 0; nf < 8; ++nf)
        acc[mf][nf] = __builtin_amdgcn_mfma_f32_16x16x32_bf16(a[mf][kk], bf[nf], acc[mf][nf], 0, 0, 0);
  }

  float bo[8], gl[8], bl[8];
#pragma unroll
  for (int nf = 0; nf < 8; ++nf) {
    int c = nf * 16 + lr;
    bo[nf] = b_out[c]; gl[nf] = g_ln[c]; bl[nf] = b_ln[c];
  }
#pragma unroll
  for (int mf = 0; mf < 2; ++mf)
#pragma unroll
    for (int nf = 0; nf < 8; ++nf)
#pragma unroll
      for (int j = 0; j < 4; ++j) acc[mf][nf][j] += bo[nf];

#pragma unroll
  for (int mf = 0; mf < 2; ++mf) {
    float s[4] = {0, 0, 0, 0}, q[4] = {0, 0, 0, 0};
#pragma unroll
    for (int nf = 0; nf < 8; ++nf)
#pragma unroll
      for (int j = 0; j < 4; ++j) {
        float v = acc[mf][nf][j];
        s[j] += v; q[j] += v * v;
      }
#pragma unroll
    for (int j = 0; j < 4; ++j) {
#pragma unroll
      for (int d = 1; d < 16; d <<= 1) {
        s[j] += __shfl_xor(s[j], d, 64);
        q[j] += __shfl_xor(q[j], d, 64);
      }
    }
#pragma unroll
    for (int j = 0; j < 4; ++j) {
      float mean = s[j] * (1.0f / 128.0f);
      float var = q[j] * (1.0f / 128.0f) - mean * mean;
      float rstd = rsqrtf(var + EPS_LN);
      size_t ro = (size_t)(rowBase + w * 32 + mf * 16 + kg * 4 + j) * 128;
#pragma unroll
      for (int nf = 0; nf < 8; ++nf)
        out[ro + nf * 16 + lr] = (acc[mf][nf][j] - mean) * rstd * gl[nf] + bl[nf];
    }
  }
}

extern "C" void kernel_launch(void* const* d_in, const int* in_sizes, int n_in,
                              void* d_out, int out_size, void* d_ws, size_t ws_size,
                              hipStream_t stream) {
  const float* x     = (const float*)d_in[0];
  const float* w_qkv = (const float*)d_in[1];
  const float* w_out = (const float*)d_in[2];
  const float* b_out = (const float*)d_in[3];
  const float* g_ln  = (const float*)d_in[4];
  const float* b_ln  = (const float*)d_in[5];
  float* out = (float*)d_out;

  char* ws = (char*)d_ws;
  unsigned short* wqkvT = (unsigned short*)(ws + 0);
  float* ctxp           = (float*)(ws + 131072);
  float* ksump          = (float*)(ws + 8519680);
  unsigned short* weffT = (unsigned short*)(ws + 8781824);
  unsigned short* eq    = (unsigned short*)(ws + 9306112);

  k_transpose_wqkv<<<96, 256, 0, stream>>>(w_qkv, wqkvT);
  k_q_exp128<<<512, 256, 0, stream>>>(x, wqkvT, eq);
  // MEASUREMENT: 5x identical launches (idempotent). kv_ctx dur = extra/4.
  k_kv_ctx<<<512, 256, 0, stream>>>(x, wqkvT, ctxp, ksump);
  k_kv_ctx<<<512, 256, 0, stream>>>(x, wqkvT, ctxp, ksump);
  k_kv_ctx<<<512, 256, 0, stream>>>(x, wqkvT, ctxp, ksump);
  k_kv_ctx<<<512, 256, 0, stream>>>(x, wqkvT, ctxp, ksump);
  k_kv_ctx<<<512, 256, 0, stream>>>(x, wqkvT, ctxp, ksump);
  k_eqnorm<<<4096, 256, 0, stream>>>(eq);
  k_weff64<<<64, 256, 0, stream>>>(ctxp, ksump, w_out, weffT);
  k_out_ln<<<512, 256, 0, stream>>>(eq, weffT, b_out, g_ln, b_ln, out);
}

// Round 15
// 86.172 us; speedup vs baseline: 1.7005x; 1.6376x over previous
//
#include <hip/hip_runtime.h>
#include <hip/hip_bf16.h>
#include <cstddef>
#include <cstdint>

// LinearAttention fused pipeline, MI355X gfx950.  == R15: clean pipeline ==
// Measured ledger (R13/R14 direct measurement rounds):
//   transpose 1.5 | q_exp128 14.5 (direct) | kv_ctx ~17-20 | eqnorm ~11
//   weff ~2.5 | out_ln ~9  => total ~56us predicted.
// Falsified across R1-R14: barrier-avoidance, load batching, input dtype,
// softmax-epilogue, occupancy. CONFIRMED lever: store/load line efficiency
// (old eqnorm's stride-64 16B/lane = 4x read amp = ~30us; fixed coalesced).
// Fused variants measured WORSE (R6 fused=43us; R9/R10 norm-in-out_ln
// ballooned via VGPR pressure) -> split pipeline is the evidence-backed best.

typedef __attribute__((ext_vector_type(8))) short short8_t;
typedef __attribute__((ext_vector_type(4))) float f32x4;

#define SCALE_Q 0.17677669529663687f
#define EPS_LN 1e-5f

__device__ __forceinline__ float bf2f(unsigned short u) {
  union { float f; unsigned u; } v; v.u = ((unsigned)u) << 16;
  return v.f;
}
__device__ __forceinline__ unsigned pack2(float f0, float f1) {
  union { float f; unsigned u; } a, b; a.f = f0; b.f = f1;
  return __builtin_amdgcn_perm(b.u, a.u, 0x07060302);
}
__device__ __forceinline__ unsigned short f2bf_rne(float f) {
  union { float f; unsigned u; } v; v.f = f;
  return (unsigned short)((v.u + 0x7FFFu + ((v.u >> 16) & 1u)) >> 16);
}
__device__ __forceinline__ unsigned pack2rne(float f0, float f1) {
  return (unsigned)f2bf_rne(f0) | ((unsigned)f2bf_rne(f1) << 16);
}
__device__ __forceinline__ short8_t trunc8(float4 lo, float4 hi) {
  union { float4 f; unsigned u[4]; } a, b;
  union { unsigned u[4]; short8_t s; } r;
  a.f = lo; b.f = hi;
  r.u[0] = __builtin_amdgcn_perm(a.u[1], a.u[0], 0x07060302);
  r.u[1] = __builtin_amdgcn_perm(a.u[3], a.u[2], 0x07060302);
  r.u[2] = __builtin_amdgcn_perm(b.u[1], b.u[0], 0x07060302);
  r.u[3] = __builtin_amdgcn_perm(b.u[3], b.u[2], 0x07060302);
  return r.s;
}

// ---------------- K1: transpose + bf16 convert w_qkv [128][384] -> [384][128]
__global__ void k_transpose_wqkv(const float* __restrict__ w,
                                 unsigned short* __restrict__ wT) {
  int c = blockIdx.x * 4 + (threadIdx.x >> 6);
  int l = threadIdx.x & 63;
  float f0 = w[(size_t)(2 * l) * 384 + c];
  float f1 = w[(size_t)(2 * l + 1) * 384 + c];
  ((unsigned*)(wT + (size_t)c * 128))[l] = pack2(f0, f1);
}

// ---------------- K2: q GEMM -> eq = exp(q) unnormalized. MEASURED 14.5us.
__global__ __launch_bounds__(256, 2)
void k_q_exp128(const float* __restrict__ x, const unsigned short* __restrict__ wT,
                unsigned short* __restrict__ eq) {
  __shared__ short Bq[128][136];

  int tid = threadIdx.x;
  int rowBase = blockIdx.x * 128;

  {
#pragma unroll
    for (int i = 0; i < 8; ++i) {
      int idx = i * 256 + tid;
      int n = idx >> 4;
      int k8 = (idx & 15) << 3;
      *(short8_t*)&Bq[n][k8] = *(const short8_t*)(wT + (size_t)n * 128 + k8);
    }
  }

  int lane = tid & 63;
  int wv = tid >> 6;
  int wr = wv >> 1, wc = wv & 1;
  int lr = lane & 15;
  int kg = lane >> 4;

  short8_t abf[4][4];
  {
    const float* ap = x + (size_t)(rowBase + wr * 64 + lr) * 128 + kg * 8;
#pragma unroll
    for (int mf = 0; mf < 4; ++mf) {
      const float* r = ap + (size_t)mf * 16 * 128;
#pragma unroll
      for (int kk = 0; kk < 4; ++kk)
        abf[kk][mf] = trunc8(*(const float4*)(r + kk * 32),
                             *(const float4*)(r + kk * 32 + 4));
    }
  }
  __syncthreads();

  f32x4 acc[4][4] = {};
#pragma unroll
  for (int kk = 0; kk < 4; ++kk) {
    short8_t bf[4];
#pragma unroll
    for (int nf = 0; nf < 4; ++nf)
      bf[nf] = *(const short8_t*)&Bq[wc * 64 + nf * 16 + lr][kk * 32 + kg * 8];
#pragma unroll
    for (int mf = 0; mf < 4; ++mf)
#pragma unroll
      for (int nf = 0; nf < 4; ++nf)
        acc[mf][nf] = __builtin_amdgcn_mfma_f32_16x16x32_bf16(abf[kk][mf], bf[nf], acc[mf][nf], 0, 0, 0);
  }

#pragma unroll
  for (int mf = 0; mf < 4; ++mf)
#pragma unroll
    for (int p = 0; p < 2; ++p)
#pragma unroll
      for (int j = 0; j < 4; ++j) {
        float e0 = __expf(acc[mf][2 * p][j]);
        float e1 = __expf(acc[mf][2 * p + 1][j]);
        int tok = rowBase + wr * 64 + mf * 16 + kg * 4 + j;
        int head = wc * 2 + p;
        *(unsigned*)&eq[(size_t)tok * 128 + head * 32 + 2 * lr] = pack2(e0, e1);
      }
}

// ---------------- K3: k+v GEMMs + in-tile ctx partial (~17-20us measured)
__global__ __launch_bounds__(256, 2)
void k_kv_ctx(const float* __restrict__ x, const unsigned short* __restrict__ wT,
              float* __restrict__ ctxp, float* __restrict__ ksump) {
  __shared__ short Bk[128][136];
  __shared__ short Bv[128][136];

  int tid = threadIdx.x;
  int rb = blockIdx.x;
  int rowBase = rb * 128;

  {
    const unsigned short* wk = wT + (size_t)1 * 128 * 128;
    const unsigned short* wv2 = wT + (size_t)2 * 128 * 128;
#pragma unroll
    for (int i = 0; i < 8; ++i) {
      int idx = i * 256 + tid;
      int n = idx >> 4;
      int k8 = (idx & 15) << 3;
      *(short8_t*)&Bk[n][k8] = *(const short8_t*)(wk + (size_t)n * 128 + k8);
      *(short8_t*)&Bv[n][k8] = *(const short8_t*)(wv2 + (size_t)n * 128 + k8);
    }
  }

  int lane = tid & 63;
  int wv = tid >> 6;
  int wr = wv >> 1, wc = wv & 1;
  int lr = lane & 15;
  int kg = lane >> 4;

  short8_t abf[4][4];
  {
    const float* ap = x + (size_t)(rowBase + wr * 64 + lr) * 128 + kg * 8;
#pragma unroll
    for (int mf = 0; mf < 4; ++mf) {
      const float* r = ap + (size_t)mf * 16 * 128;
#pragma unroll
      for (int kk = 0; kk < 4; ++kk)
        abf[kk][mf] = trunc8(*(const float4*)(r + kk * 32),
                             *(const float4*)(r + kk * 32 + 4));
    }
  }
  __syncthreads();

  uint2 ekp[4][4], vp[4][4];
  {
    f32x4 acc[4][4] = {};
#pragma unroll
    for (int kk = 0; kk < 4; ++kk) {
      short8_t bf[4];
#pragma unroll
      for (int nf = 0; nf < 4; ++nf)
        bf[nf] = *(const short8_t*)&Bk[wc * 64 + nf * 16 + lr][kk * 32 + kg * 8];
#pragma unroll
      for (int mf = 0; mf < 4; ++mf)
#pragma unroll
        for (int nf = 0; nf < 4; ++nf)
          acc[mf][nf] = __builtin_amdgcn_mfma_f32_16x16x32_bf16(abf[kk][mf], bf[nf], acc[mf][nf], 0, 0, 0);
    }
#pragma unroll
    for (int mf = 0; mf < 4; ++mf)
#pragma unroll
      for (int nf = 0; nf < 4; ++nf) {
        ekp[mf][nf].x = pack2(__expf(acc[mf][nf][0]), __expf(acc[mf][nf][1]));
        ekp[mf][nf].y = pack2(__expf(acc[mf][nf][2]), __expf(acc[mf][nf][3]));
      }
  }
  {
    f32x4 acc[4][4] = {};
#pragma unroll
    for (int kk = 0; kk < 4; ++kk) {
      short8_t bf[4];
#pragma unroll
      for (int nf = 0; nf < 4; ++nf)
        bf[nf] = *(const short8_t*)&Bv[wc * 64 + nf * 16 + lr][kk * 32 + kg * 8];
#pragma unroll
      for (int mf = 0; mf < 4; ++mf)
#pragma unroll
        for (int nf = 0; nf < 4; ++nf)
          acc[mf][nf] = __builtin_amdgcn_mfma_f32_16x16x32_bf16(abf[kk][mf], bf[nf], acc[mf][nf], 0, 0, 0);
    }
#pragma unroll
    for (int mf = 0; mf < 4; ++mf)
#pragma unroll
      for (int nf = 0; nf < 4; ++nf) {
        vp[mf][nf].x = pack2(acc[mf][nf][0], acc[mf][nf][1]);
        vp[mf][nf].y = pack2(acc[mf][nf][2], acc[mf][nf][3]);
      }
  }
  __syncthreads();

  short (*ekT)[136] = Bk;
  short (*vT)[136] = Bv;
#pragma unroll
  for (int mf = 0; mf < 4; ++mf) {
    int t0 = wr * 64 + mf * 16 + kg * 4;
#pragma unroll
    for (int nf = 0; nf < 4; ++nf) {
      int col = wc * 64 + nf * 16 + lr;
      *(uint2*)&ekT[col][t0] = ekp[mf][nf];
      *(uint2*)&vT[col][t0] = vp[mf][nf];
    }
  }
  __syncthreads();

  {
    int h = wv;
    f32x4 c2[2][2] = {};
#pragma unroll
    for (int kk = 0; kk < 4; ++kk) {
      short8_t a2[2], b2[2];
#pragma unroll
      for (int m2 = 0; m2 < 2; ++m2)
        a2[m2] = *(const short8_t*)&ekT[h * 32 + m2 * 16 + lr][kk * 32 + kg * 8];
#pragma unroll
      for (int n2 = 0; n2 < 2; ++n2)
        b2[n2] = *(const short8_t*)&vT[h * 32 + n2 * 16 + lr][kk * 32 + kg * 8];
#pragma unroll
      for (int m2 = 0; m2 < 2; ++m2)
#pragma unroll
        for (int n2 = 0; n2 < 2; ++n2)
          c2[m2][n2] = __builtin_amdgcn_mfma_f32_16x16x32_bf16(a2[m2], b2[n2], c2[m2][n2], 0, 0, 0);
    }
    float* cp = ctxp + ((size_t)rb * 4 + h) * 1024;
#pragma unroll
    for (int m2 = 0; m2 < 2; ++m2)
#pragma unroll
      for (int n2 = 0; n2 < 2; ++n2)
#pragma unroll
        for (int j = 0; j < 4; ++j)
          cp[(m2 * 16 + kg * 4 + j) * 32 + n2 * 16 + lr] = c2[m2][n2][j];
  }

  if (tid < 128) {
    float s = 0;
#pragma unroll
    for (int t8 = 0; t8 < 128; t8 += 8) {
      short8_t v8 = *(const short8_t*)&ekT[tid][t8];
#pragma unroll
      for (int i = 0; i < 8; ++i) s += bf2f((unsigned short)v8[i]);
    }
    ksump[(size_t)rb * 128 + tid] = s;
  }
}

// ---------------- K4: COALESCED eq normalization (~11us, at its roofline)
__global__ void k_eqnorm(unsigned short* __restrict__ eq) {
  int idx = blockIdx.x * 256 + threadIdx.x;
  uint4* p = (uint4*)eq + idx;
  uint4 v = *p;
  const unsigned* u = (const unsigned*)&v;
  float f[8];
#pragma unroll
  for (int q = 0; q < 4; ++q) {
    f[2 * q]     = bf2f((unsigned short)(u[q] & 0xFFFFu));
    f[2 * q + 1] = bf2f((unsigned short)(u[q] >> 16));
  }
  float s = 0;
#pragma unroll
  for (int i = 0; i < 8; ++i) s += f[i];
  s += __shfl_xor(s, 1, 64);
  s += __shfl_xor(s, 2, 64);
  float r = SCALE_Q / s;
  unsigned o0 = pack2rne(f[0] * r, f[1] * r);
  unsigned o1 = pack2rne(f[2] * r, f[3] * r);
  unsigned o2 = pack2rne(f[4] * r, f[5] * r);
  unsigned o3 = pack2rne(f[6] * r, f[7] * r);
  *p = make_uint4(o0, o1, o2, o3);
}

// ---------------- K5: per (b,h) reduce partials + build W_eff^T cols
__global__ __launch_bounds__(256, 4)
void k_weff64(const float* __restrict__ ctxp, const float* __restrict__ ksump,
              const float* __restrict__ wout, unsigned short* __restrict__ weffT) {
  __shared__ float wo[32][128];
  __shared__ float cn[32][32];
  __shared__ float ksh[32];
  int tid = threadIdx.x;
  int b = blockIdx.x >> 2, h = blockIdx.x & 3;

#pragma unroll
  for (int i = 0; i < 16; ++i) {
    int idx = i * 256 + tid;
    int e = idx >> 7, jj = idx & 127;
    wo[e][jj] = wout[(h * 32 + e) * 128 + jj];
  }
  if (tid < 32) {
    float s = 0;
    for (int c = 0; c < 32; ++c)
      s += ksump[(size_t)(b * 32 + c) * 128 + h * 32 + tid];
    ksh[tid] = s;
  }
  __syncthreads();
#pragma unroll
  for (int i = 0; i < 4; ++i) {
    int idx = i * 256 + tid;
    int d = idx >> 5;
    float s = 0;
    for (int c = 0; c < 32; ++c)
      s += ctxp[((size_t)(b * 32 + c) * 4 + h) * 1024 + idx];
    cn[d][idx & 31] = s / ksh[d];
  }
  __syncthreads();

  int j = tid >> 1, h8 = (tid & 1) * 8;
  unsigned pk[8];
#pragma unroll
  for (int t = 0; t < 8; ++t) {
    int dd = h8 + t;
    float s0 = 0, s1 = 0;
#pragma unroll
    for (int e = 0; e < 32; ++e) {
      float w = wo[e][j];
      s0 += cn[dd][e] * w;
      s1 += cn[16 + dd][e] * w;
    }
    pk[t] = pack2(s0, s1);
  }
  unsigned* outp = (unsigned*)(weffT + (size_t)b * 16384 + j * 128 + h * 32 + 2 * h8);
  *(uint4*)outp = make_uint4(pk[0], pk[1], pk[2], pk[3]);
  *(uint4*)(outp + 4) = make_uint4(pk[4], pk[5], pk[6], pk[7]);
}

// ---------------- K6: out = LN( eq @ W_eff[b] + b_out )  (~9us, at roofline)
__global__ __launch_bounds__(256, 2)
void k_out_ln(const unsigned short* __restrict__ eq, const unsigned short* __restrict__ weffT,
              const float* __restrict__ b_out, const float* __restrict__ g_ln,
              const float* __restrict__ b_ln, float* __restrict__ out) {
  int tid = threadIdx.x;
  int rowBase = blockIdx.x * 128;
  int b = rowBase >> 12;
  int lane = tid & 63;
  int w = tid >> 6;
  int lr = lane & 15;
  int kg = lane >> 4;

  const unsigned short* bb = weffT + (size_t)b * 16384;

  short8_t a[2][4];
  {
    const unsigned short* ap = eq + (size_t)(rowBase + w * 32 + lr) * 128 + kg * 8;
#pragma unroll
    for (int mf = 0; mf < 2; ++mf)
#pragma unroll
      for (int kk = 0; kk < 4; ++kk)
        a[mf][kk] = *(const short8_t*)(ap + (size_t)mf * 16 * 128 + kk * 32);
  }

  f32x4 acc[2][8] = {};
#pragma unroll
  for (int kk = 0; kk < 4; ++kk) {
    short8_t bf[8];
#pragma unroll
    for (int nf = 0; nf < 8; ++nf)
      bf[nf] = *(const short8_t*)(bb + (size_t)(nf * 16 + lr) * 128 + kk * 32 + kg * 8);
#pragma unroll
    for (int mf = 0; mf < 2; ++mf)
#pragma unroll
      for (int nf = 0; nf < 8; ++nf)
        acc[mf][nf] = __builtin_amdgcn_mfma_f32_16x16x32_bf16(a[mf][kk], bf[nf], acc[mf][nf], 0, 0, 0);
  }

  float bo[8], gl[8], bl[8];
#pragma unroll
  for (int nf = 0; nf < 8; ++nf) {
    int c = nf * 16 + lr;
    bo[nf] = b_out[c]; gl[nf] = g_ln[c]; bl[nf] = b_ln[c];
  }
#pragma unroll
  for (int mf = 0; mf < 2; ++mf)
#pragma unroll
    for (int nf = 0; nf < 8; ++nf)
#pragma unroll
      for (int j = 0; j < 4; ++j) acc[mf][nf][j] += bo[nf];

#pragma unroll
  for (int mf = 0; mf < 2; ++mf) {
    float s[4] = {0, 0, 0, 0}, q[4] = {0, 0, 0, 0};
#pragma unroll
    for (int nf = 0; nf < 8; ++nf)
#pragma unroll
      for (int j = 0; j < 4; ++j) {
        float v = acc[mf][nf][j];
        s[j] += v; q[j] += v * v;
      }
#pragma unroll
    for (int j = 0; j < 4; ++j) {
#pragma unroll
      for (int d = 1; d < 16; d <<= 1) {
        s[j] += __shfl_xor(s[j], d, 64);
        q[j] += __shfl_xor(q[j], d, 64);
      }
    }
#pragma unroll
    for (int j = 0; j < 4; ++j) {
      float mean = s[j] * (1.0f / 128.0f);
      float var = q[j] * (1.0f / 128.0f) - mean * mean;
      float rstd = rsqrtf(var + EPS_LN);
      size_t ro = (size_t)(rowBase + w * 32 + mf * 16 + kg * 4 + j) * 128;
#pragma unroll
      for (int nf = 0; nf < 8; ++nf)
        out[ro + nf * 16 + lr] = (acc[mf][nf][j] - mean) * rstd * gl[nf] + bl[nf];
    }
  }
}

extern "C" void kernel_launch(void* const* d_in, const int* in_sizes, int n_in,
                              void* d_out, int out_size, void* d_ws, size_t ws_size,
                              hipStream_t stream) {
  const float* x     = (const float*)d_in[0];
  const float* w_qkv = (const float*)d_in[1];
  const float* w_out = (const float*)d_in[2];
  const float* b_out = (const float*)d_in[3];
  const float* g_ln  = (const float*)d_in[4];
  const float* b_ln  = (const float*)d_in[5];
  float* out = (float*)d_out;

  char* ws = (char*)d_ws;
  unsigned short* wqkvT = (unsigned short*)(ws + 0);
  float* ctxp           = (float*)(ws + 131072);
  float* ksump          = (float*)(ws + 8519680);
  unsigned short* weffT = (unsigned short*)(ws + 8781824);
  unsigned short* eq    = (unsigned short*)(ws + 9306112);

  k_transpose_wqkv<<<96, 256, 0, stream>>>(w_qkv, wqkvT);
  k_q_exp128<<<512, 256, 0, stream>>>(x, wqkvT, eq);
  k_kv_ctx<<<512, 256, 0, stream>>>(x, wqkvT, ctxp, ksump);
  k_eqnorm<<<4096, 256, 0, stream>>>(eq);
  k_weff64<<<64, 256, 0, stream>>>(ctxp, ksump, w_out, weffT);
  k_out_ln<<<512, 256, 0, stream>>>(eq, weffT, b_out, g_ln, b_ln, out);
}